// Round 19
// baseline (2004.316 us; speedup 1.0000x reference)
//
#include <hip/hip_runtime.h>
#include <hip/hip_bf16.h>
#include <math.h>

#define D_MODEL 768
#define NHEAD 12
#define DHEAD 64
#define NLAYER 12
#define FF_DIM 3072
#define SEQ 1024
#define TOKENS 2048   /* B*T */
#define VOCAB 50257

typedef short bf16x8 __attribute__((ext_vector_type(8)));
typedef float f32x4 __attribute__((ext_vector_type(4)));
typedef unsigned short u16x4 __attribute__((ext_vector_type(4)));
typedef unsigned short u16x8 __attribute__((ext_vector_type(8)));

__device__ inline unsigned short f2bf(float f) {
    union { float f; unsigned u; } un;
    un.f = f;
    unsigned u = un.u;
    u += 0x7fffu + ((u >> 16) & 1u);   // RTNE
    return (unsigned short)(u >> 16);
}

// async 16B global->LDS (dest must be wave-uniform base; HW adds lane*16)
__device__ inline void gl_lds16(const void* g, void* l) {
    __builtin_amdgcn_global_load_lds(
        (const __attribute__((address_space(1))) unsigned int*)g,
        (__attribute__((address_space(3))) unsigned int*)l, 16, 0, 0);
}

// counted vmcnt wait (T4): immediate must be a literal
template<int N> __device__ __forceinline__ void waitcnt_vm() {
    static_assert(N == 0 || N == 3 || N == 4 || N == 5 || N == 6 || N == 8, "add case");
    if constexpr (N == 0) asm volatile("s_waitcnt vmcnt(0)" ::: "memory");
    else if constexpr (N == 3) asm volatile("s_waitcnt vmcnt(3)" ::: "memory");
    else if constexpr (N == 4) asm volatile("s_waitcnt vmcnt(4)" ::: "memory");
    else if constexpr (N == 5) asm volatile("s_waitcnt vmcnt(5)" ::: "memory");
    else if constexpr (N == 6) asm volatile("s_waitcnt vmcnt(6)" ::: "memory");
    else if constexpr (N == 8) asm volatile("s_waitcnt vmcnt(8)" ::: "memory");
}

// ---------------- fp32 -> bf16 bulk convert ----------------
__global__ __launch_bounds__(256) void cvt_kernel(const float* __restrict__ s,
                                                  unsigned short* __restrict__ d,
                                                  long n4) {
    long i = (long)blockIdx.x * 256 + threadIdx.x;
    long stride = (long)gridDim.x * 256;
    for (; i < n4; i += stride) {
        f32x4 v = ((const f32x4*)s)[i];
        u16x4 r;
        r[0] = f2bf(v[0]); r[1] = f2bf(v[1]); r[2] = f2bf(v[2]); r[3] = f2bf(v[3]);
        ((u16x4*)d)[i] = r;
    }
}

// ---------------- embedding ----------------
__global__ __launch_bounds__(256) void embed_kernel(const int* __restrict__ ids,
                                                    const float* __restrict__ tok,
                                                    const float* __restrict__ pos,
                                                    float* __restrict__ x) {
    int i = blockIdx.x * 256 + threadIdx.x;          // over TOKENS*D_MODEL
    int row = i / D_MODEL;
    int d = i - row * D_MODEL;
    int t = row & (SEQ - 1);
    x[i] = tok[(long)ids[row] * D_MODEL + d] + pos[(long)t * D_MODEL + d];
}

// ---------------- layernorm (fp32 in, bf16 out) ----------------
__global__ __launch_bounds__(256) void ln_kernel(const float* __restrict__ x,
                                                 const float* __restrict__ g,
                                                 const float* __restrict__ b,
                                                 unsigned short* __restrict__ out) {
    int row = blockIdx.x;
    int tid = threadIdx.x;
    const float* xr = x + (long)row * D_MODEL;
    float v0 = xr[tid], v1 = xr[tid + 256], v2 = xr[tid + 512];
    __shared__ float sm[4];
    float s = v0 + v1 + v2;
    #pragma unroll
    for (int off = 32; off; off >>= 1) s += __shfl_xor(s, off);
    if ((tid & 63) == 0) sm[tid >> 6] = s;
    __syncthreads();
    float mean = (sm[0] + sm[1] + sm[2] + sm[3]) * (1.f / D_MODEL);
    __syncthreads();
    float d0 = v0 - mean, d1 = v1 - mean, d2 = v2 - mean;
    s = d0 * d0 + d1 * d1 + d2 * d2;
    #pragma unroll
    for (int off = 32; off; off >>= 1) s += __shfl_xor(s, off);
    if ((tid & 63) == 0) sm[tid >> 6] = s;
    __syncthreads();
    float var = (sm[0] + sm[1] + sm[2] + sm[3]) * (1.f / D_MODEL);
    float rs = rsqrtf(var + 1e-5f);
    unsigned short* orow = out + (long)row * D_MODEL;
    orow[tid]       = f2bf(d0 * rs * g[tid]       + b[tid]);
    orow[tid + 256] = f2bf(d1 * rs * g[tid + 256] + b[tid + 256]);
    orow[tid + 512] = f2bf(d2 * rs * g[tid + 512] + b[tid + 512]);
}

// ---------------- GEMM: C[M][N] = A_bf16[M][K] @ W_bf16[N][K]^T ----------------
#define GM_NONE 0
#define GM_RES  1
#define GM_GELU 2
#define GM_QKV  3

template<int WM, int WN, int MODE, int DB>
__global__ __launch_bounds__(256) void gemm_bf16(
        const unsigned short* __restrict__ A, const unsigned short* __restrict__ W,
        int M, int N, int K,
        float* __restrict__ Cf, unsigned short* __restrict__ Cb,
        const float* __restrict__ RES,
        unsigned short* __restrict__ P1, unsigned short* __restrict__ P2) {
    constexpr int BM = WM * 32, BN = WN * 32;
    constexpr int NLD = BM / 32 + BN / 32;   // gl_lds issues per stage()
    __shared__ unsigned short lA[DB][BM * 64];
    __shared__ unsigned short lB[DB][BN * 64];

    int tid = threadIdx.x;
    int lane = tid & 63, wv = tid >> 6;
    int wr = wv >> 1, wc = wv & 1;
    int lr = lane & 15, kq = lane >> 4;
    int row0 = blockIdx.x * BM;
    int col0 = blockIdx.y * BN;

    int srow_in = tid >> 3;
    int ssp = tid & 7;
    int skg = ssp ^ (srow_in & 7);
    int lbase = ((tid & ~63)) << 3;

    f32x4 acc[WM][WN];
    #pragma unroll
    for (int m = 0; m < WM; m++)
        #pragma unroll
        for (int n = 0; n < WN; n++) acc[m][n] = (f32x4){0.f, 0.f, 0.f, 0.f};

    auto stage = [&](int buf, int kt) {
        #pragma unroll
        for (int i = 0; i < BM / 32; i++) {
            int row = i * 32 + srow_in;
            gl_lds16(A + (size_t)(row0 + row) * K + kt + skg * 8,
                     &lA[buf][i * 2048 + lbase]);
        }
        #pragma unroll
        for (int i = 0; i < BN / 32; i++) {
            int row = i * 32 + srow_in;
            int srow = col0 + row;
            if (srow >= N) srow = N - 1;
            gl_lds16(W + (size_t)srow * K + kt + skg * 8,
                     &lB[buf][i * 2048 + lbase]);
        }
    };
    auto compute = [&](int buf) {
        #pragma unroll
        for (int kk = 0; kk < 2; kk++) {
            int kg = kk * 4 + kq;
            bf16x8 af[WM], bfr[WN];
            #pragma unroll
            for (int m = 0; m < WM; m++) {
                int row = wr * (WM * 16) + m * 16 + lr;
                af[m] = *(const bf16x8*)&lA[buf][row * 64 + ((kg ^ (row & 7)) << 3)];
            }
            #pragma unroll
            for (int n = 0; n < WN; n++) {
                int row = wc * (WN * 16) + n * 16 + lr;
                bfr[n] = *(const bf16x8*)&lB[buf][row * 64 + ((kg ^ (row & 7)) << 3)];
            }
            #pragma unroll
            for (int m = 0; m < WM; m++)
                #pragma unroll
                for (int n = 0; n < WN; n++)
                    acc[m][n] = __builtin_amdgcn_mfma_f32_16x16x32_bf16(af[m], bfr[n], acc[m][n], 0, 0, 0);
        }
    };

    if (DB == 2) {
        stage(0, 0);
        __builtin_amdgcn_sched_barrier(0);
        int nt = K >> 6;
        int cur = 0;
        for (int t = 0; t < nt; t++) {
            if (t + 1 < nt) {
                stage(cur ^ 1, (t + 1) << 6);
                __builtin_amdgcn_sched_barrier(0);
                waitcnt_vm<NLD>();      // tile t's loads done; t+1's stay in flight
            } else {
                waitcnt_vm<0>();
            }
            __builtin_amdgcn_s_barrier();
            __builtin_amdgcn_sched_barrier(0);
            compute(cur);
            __builtin_amdgcn_sched_barrier(0);
            __builtin_amdgcn_s_barrier();   // WAR: all reads of cur done before re-stage
            cur ^= 1;
        }
    } else {
        for (int kt = 0; kt < K; kt += 64) {
            stage(0, kt);
            __syncthreads();
            compute(0);
            __syncthreads();
        }
    }

    // ---- epilogue ----
    #pragma unroll
    for (int m = 0; m < WM; m++) {
        int r0 = row0 + wr * (WM * 16) + m * 16 + (kq << 2);
        #pragma unroll
        for (int n = 0; n < WN; n++) {
            int c = col0 + wc * (WN * 16) + n * 16 + lr;
            if (c < N) {
                if (MODE == GM_QKV) {
                    int bb = r0 >> 10, t0q = r0 & 1023;   // 4 consecutive tokens, same b
                    if (c < D_MODEL) {
                        int h = c >> 6, dh = c & 63;
                        size_t base = (((size_t)(bb * NHEAD + h) * SEQ) + t0q) * 64 + dh;
                        #pragma unroll
                        for (int j = 0; j < 4; j++)
                            P1[base + (size_t)j * 64] = f2bf(acc[m][n][j] * 0.125f);
                    } else if (c < 2 * D_MODEL) {
                        int cc = c - D_MODEL;
                        int h = cc >> 6, dh = cc & 63;
                        size_t base = (((size_t)(bb * NHEAD + h) * SEQ) + t0q) * 64 + dh;
                        #pragma unroll
                        for (int j = 0; j < 4; j++)
                            P2[base + (size_t)j * 64] = f2bf(acc[m][n][j]);
                    } else {
                        int cc = c - 2 * D_MODEL;
                        int h = cc >> 6, dh = cc & 63;
                        u16x4 vv;
                        #pragma unroll
                        for (int j = 0; j < 4; j++) vv[j] = f2bf(acc[m][n][j]);
                        *(u16x4*)(Cb + ((size_t)(bb * NHEAD + h) * 64 + dh) * SEQ + t0q) = vv;
                    }
                } else {
                    #pragma unroll
                    for (int j = 0; j < 4; j++) {
                        int r = r0 + j;
                        size_t idx = (size_t)r * N + c;
                        float v = acc[m][n][j];
                        if (MODE == GM_RES) {
                            Cf[idx] = v + RES[idx];
                        } else if (MODE == GM_GELU) {
                            Cb[idx] = f2bf(0.5f * v * (1.f + erff(v * 0.70710678118f)));
                        } else {
                            Cf[idx] = v;
                        }
                    }
                }
            }
        }
    }
}

// ---------------- 256x256 GEMM for the logits shape (r15 proven: 296us) ----------------
__global__ __launch_bounds__(512, 2) void gemm256_bf16(
        const unsigned short* __restrict__ A, const unsigned short* __restrict__ W,
        int M, int N, int K, float* __restrict__ Cf) {
    __shared__ unsigned short lA[2][256 * 64];   // 64 KB
    __shared__ unsigned short lB[2][256 * 64];   // 64 KB

    int tid = threadIdx.x;
    int lane = tid & 63, wv = tid >> 6;
    int wr = wv >> 2, wc = wv & 3;               // 2 x 4 waves
    int lr = lane & 15, kq = lane >> 4;
    int row0 = blockIdx.x * 256;
    int col0 = blockIdx.y * 256;

    int srow_in = tid >> 3;                      // 0..63 per issue
    int skg = (tid & 7) ^ (srow_in & 7);
    int lbase = (tid & ~63) << 3;                // wv*512 ushorts

    f32x4 acc[8][4];
    #pragma unroll
    for (int m = 0; m < 8; m++)
        #pragma unroll
        for (int n = 0; n < 4; n++) acc[m][n] = (f32x4){0.f, 0.f, 0.f, 0.f};

    auto stage = [&](int buf, int kt) {
        #pragma unroll
        for (int i = 0; i < 4; i++) {
            int row = i * 64 + srow_in;
            gl_lds16(A + (size_t)(row0 + row) * K + kt + skg * 8,
                     &lA[buf][i * 4096 + lbase]);
        }
        #pragma unroll
        for (int i = 0; i < 4; i++) {
            int row = i * 64 + srow_in;
            int srow = col0 + row;
            if (srow >= N) srow = N - 1;
            gl_lds16(W + (size_t)srow * K + kt + skg * 8,
                     &lB[buf][i * 4096 + lbase]);
        }
    };
    auto compute = [&](int buf) {
        #pragma unroll
        for (int kk = 0; kk < 2; kk++) {
            int kg = kk * 4 + kq;
            bf16x8 af[8], bfr[4];
            #pragma unroll
            for (int m = 0; m < 8; m++) {
                int row = wr * 128 + m * 16 + lr;
                af[m] = *(const bf16x8*)&lA[buf][row * 64 + ((kg ^ (row & 7)) << 3)];
            }
            #pragma unroll
            for (int n = 0; n < 4; n++) {
                int row = wc * 64 + n * 16 + lr;
                bfr[n] = *(const bf16x8*)&lB[buf][row * 64 + ((kg ^ (row & 7)) << 3)];
            }
            #pragma unroll
            for (int m = 0; m < 8; m++)
                #pragma unroll
                for (int n = 0; n < 4; n++)
                    acc[m][n] = __builtin_amdgcn_mfma_f32_16x16x32_bf16(af[m], bfr[n], acc[m][n], 0, 0, 0);
        }
    };

    stage(0, 0);
    __builtin_amdgcn_sched_barrier(0);
    int nt = K >> 6;
    int cur = 0;
    for (int t = 0; t < nt; t++) {
        if (t + 1 < nt) {
            stage(cur ^ 1, (t + 1) << 6);
            __builtin_amdgcn_sched_barrier(0);
            waitcnt_vm<8>();             // tile t's 8 loads done; t+1's in flight
        } else {
            waitcnt_vm<0>();
        }
        __builtin_amdgcn_s_barrier();
        __builtin_amdgcn_sched_barrier(0);
        compute(cur);
        __builtin_amdgcn_sched_barrier(0);
        __builtin_amdgcn_s_barrier();
        cur ^= 1;
    }

    #pragma unroll
    for (int m = 0; m < 8; m++) {
        int r0 = row0 + wr * 128 + m * 16 + (kq << 2);
        #pragma unroll
        for (int n = 0; n < 4; n++) {
            int c = col0 + wc * 64 + n * 16 + lr;
            if (c < N) {
                #pragma unroll
                for (int j = 0; j < 4; j++)
                    Cf[(size_t)(r0 + j) * N + c] = acc[m][n][j];
            }
        }
    }
}

// ---------------- MFMA flash attention (dual-tile K/V-share + T13 + T5) ----------------
// r18: defer-max (THR=8): skip O/l rescale when no row max grew by >8 — saves
// 4 corr exps + 16 O-scale VALU per chunk per tile (common case). s_setprio(1)
// around MFMA clusters (waves at different chunk phases -> T5 regime).
#define ANW 4
__global__ __launch_bounds__(256) void attn_mfma(const unsigned short* __restrict__ Qb,
                                                 const unsigned short* __restrict__ Kb,
                                                 const unsigned short* __restrict__ Vt,
                                                 unsigned short* __restrict__ att) {
    int b = blockIdx.z, h = blockIdx.y, pr = blockIdx.x;
    int tid = threadIdx.x, l = tid & 63, w = tid >> 6;
    int lr = l & 15, hg = l >> 4;
    int hk8 = hg * 8, hg4 = hg * 4;
    size_t bh = (size_t)b * NHEAD + h;
    const unsigned short* Qp = Qb + bh * SEQ * 64;
    const unsigned short* Kp = Kb + bh * SEQ * 64;
    const unsigned short* Vp = Vt + bh * 64 * SEQ;

    __shared__ float sm_m[ANW][2][16], sm_l[ANW][2][16];
    __shared__ float sm_o[ANW][2][16][65];
    __shared__ unsigned short pl[ANW][1024];
    unsigned short* Pw = &pl[w][0];

    int tlo = pr, thi = 63 - pr;
    int q0lo = tlo * 16, q0hi = thi * 16;
    int nlo = (tlo >> 2) + 1, nhi = (thi >> 2) + 1;

    bf16x8 qlo0 = *(const bf16x8*)(Qp + (size_t)(q0lo + lr) * 64 + hk8);
    bf16x8 qlo1 = *(const bf16x8*)(Qp + (size_t)(q0lo + lr) * 64 + 32 + hk8);
    bf16x8 qhi0 = *(const bf16x8*)(Qp + (size_t)(q0hi + lr) * 64 + hk8);
    bf16x8 qhi1 = *(const bf16x8*)(Qp + (size_t)(q0hi + lr) * 64 + 32 + hk8);

    f32x4 Olo[4], Ohi[4];
    #pragma unroll
    for (int dt = 0; dt < 4; dt++) { Olo[dt] = (f32x4){0,0,0,0}; Ohi[dt] = (f32x4){0,0,0,0}; }
    f32x4 mlo = (f32x4){-1e30f,-1e30f,-1e30f,-1e30f}, llo = (f32x4){0,0,0,0};
    f32x4 mhi = mlo, lhi = llo;

    bf16x8 kfa[8];
    {
        int k0p = w * 64;
        #pragma unroll
        for (int kt = 0; kt < 4; kt++) {
            kfa[2 * kt]     = *(const bf16x8*)(Kp + (size_t)(k0p + kt * 16 + lr) * 64 + hk8);
            kfa[2 * kt + 1] = *(const bf16x8*)(Kp + (size_t)(k0p + kt * 16 + lr) * 64 + 32 + hk8);
        }
    }

    for (int c = w; c < nhi; c += ANW) {
        int k0 = c * 64;
        bool dolo = (c < nlo);
        // ---- QK^T hi ----
        f32x4 S[4];
        __builtin_amdgcn_s_setprio(1);
        #pragma unroll
        for (int kt = 0; kt < 4; kt++) {
            S[kt] = (f32x4){0,0,0,0};
            S[kt] = __builtin_amdgcn_mfma_f32_16x16x32_bf16(qhi0, kfa[2 * kt], S[kt], 0, 0, 0);
            S[kt] = __builtin_amdgcn_mfma_f32_16x16x32_bf16(qhi1, kfa[2 * kt + 1], S[kt], 0, 0, 0);
        }
        __builtin_amdgcn_s_setprio(0);
        // prefetch next chunk's K frags
        bf16x8 kfb[8];
        int cn = c + ANW;
        if (cn < nhi) {
            int k0n = cn * 64;
            #pragma unroll
            for (int kt = 0; kt < 4; kt++) {
                kfb[2 * kt]     = *(const bf16x8*)(Kp + (size_t)(k0n + kt * 16 + lr) * 64 + hk8);
                kfb[2 * kt + 1] = *(const bf16x8*)(Kp + (size_t)(k0n + kt * 16 + lr) * 64 + 32 + hk8);
            }
        }
        // V frags (shared by both tiles), issued early
        bf16x8 vfr[8];
        #pragma unroll
        for (int dt = 0; dt < 4; dt++) {
            vfr[2 * dt]     = *(const bf16x8*)(Vp + (size_t)(dt * 16 + lr) * SEQ + k0 + hk8);
            vfr[2 * dt + 1] = *(const bf16x8*)(Vp + (size_t)(dt * 16 + lr) * SEQ + k0 + 32 + hk8);
        }
        // ---- hi: mask, softmax (defer-max), P->LDS, PV ----
        if (c == nhi - 1) {
            #pragma unroll
            for (int kt = 0; kt < 4; kt++)
                #pragma unroll
                for (int j = 0; j < 4; j++)
                    S[kt][j] = (k0 + kt * 16 + lr <= q0hi + hg4 + j) ? S[kt][j] : -3.0e38f;
        }
        {
            f32x4 rm;
            #pragma unroll
            for (int j = 0; j < 4; j++)
                rm[j] = fmaxf(fmaxf(S[0][j], S[1][j]), fmaxf(S[2][j], S[3][j]));
            #pragma unroll
            for (int msk = 1; msk <= 8; msk <<= 1)
                #pragma unroll
                for (int j = 0; j < 4; j++)
                    rm[j] = fmaxf(rm[j], __shfl_xor(rm[j], msk));
            bool grow = false;
            #pragma unroll
            for (int j = 0; j < 4; j++) grow = grow || (rm[j] > mhi[j] + 8.f);
            f32x4 rs = (f32x4){0,0,0,0};
            if (__any(grow)) {
                f32x4 mn, corr;
                #pragma unroll
                for (int j = 0; j < 4; j++) {
                    mn[j] = fmaxf(mhi[j], rm[j]);
                    corr[j] = __expf(mhi[j] - mn[j]);
                }
                #pragma unroll
                for (int kt = 0; kt < 4; kt++)
                    #pragma unroll
                    for (int j = 0; j < 4; j++) {
                        float p = __expf(S[kt][j] - mn[j]);
                        S[kt][j] = p;
                        rs[j] += p;
                    }
                #pragma unroll
                for (int msk = 1; msk <= 8; msk <<= 1)
                    #pragma unroll
                    for (int j = 0; j < 4; j++)
                        rs[j] += __shfl_xor(rs[j], msk);
                #pragma unroll
                for (int j = 0; j < 4; j++) {
                    lhi[j] = lhi[j] * corr[j] + rs[j];
                    mhi[j] = mn[j];
                }
                #pragma unroll
                for (int dt = 0; dt < 4; dt++)
                    #pragma unroll
                    for (int j = 0; j < 4; j++) Ohi[dt][j] *= corr[j];
            } else {
                #pragma unroll
                for (int kt = 0; kt < 4; kt++)
                    #pragma unroll
                    for (int j = 0; j < 4; j++) {
                        float p = __expf(S[kt][j] - mhi[j]);
                        S[kt][j] = p;
                        rs[j] += p;
                    }
                #pragma unroll
                for (int msk = 1; msk <= 8; msk <<= 1)
                    #pragma unroll
                    for (int j = 0; j < 4; j++)
                        rs[j] += __shfl_xor(rs[j], msk);
                #pragma unroll
                for (int j = 0; j < 4; j++) lhi[j] += rs[j];
            }
            #pragma unroll
            for (int kt = 0; kt < 4; kt++) {
                int cc = kt * 16 + lr;
                int slot = cc >> 3, off = cc & 7;
                #pragma unroll
                for (int j = 0; j < 4; j++) {
                    int r = hg4 + j;
                    Pw[r * 64 + ((slot ^ (r & 7)) << 3) + off] = f2bf(S[kt][j]);
                }
            }
            asm volatile("s_waitcnt lgkmcnt(0)" ::: "memory");
            bf16x8 pf0 = *(const bf16x8*)&Pw[lr * 64 + ((hg ^ (lr & 7)) << 3)];
            bf16x8 pf1 = *(const bf16x8*)&Pw[lr * 64 + (((4 + hg) ^ (lr & 7)) << 3)];
            __builtin_amdgcn_s_setprio(1);
            #pragma unroll
            for (int dt = 0; dt < 4; dt++) {
                Ohi[dt] = __builtin_amdgcn_mfma_f32_16x16x32_bf16(pf0, vfr[2 * dt], Ohi[dt], 0, 0, 0);
                Ohi[dt] = __builtin_amdgcn_mfma_f32_16x16x32_bf16(pf1, vfr[2 * dt + 1], Ohi[dt], 0, 0, 0);
            }
            __builtin_amdgcn_s_setprio(0);
        }
        // ---- lo: QK (shared kfa), mask, softmax (defer-max), P->LDS, PV (shared vfr) ----
        if (dolo) {
            __builtin_amdgcn_s_setprio(1);
            #pragma unroll
            for (int kt = 0; kt < 4; kt++) {
                S[kt] = (f32x4){0,0,0,0};
                S[kt] = __builtin_amdgcn_mfma_f32_16x16x32_bf16(qlo0, kfa[2 * kt], S[kt], 0, 0, 0);
                S[kt] = __builtin_amdgcn_mfma_f32_16x16x32_bf16(qlo1, kfa[2 * kt + 1], S[kt], 0, 0, 0);
            }
            __builtin_amdgcn_s_setprio(0);
            if (c == nlo - 1) {
                #pragma unroll
                for (int kt = 0; kt < 4; kt++)
                    #pragma unroll
                    for (int j = 0; j < 4; j++)
                        S[kt][j] = (k0 + kt * 16 + lr <= q0lo + hg4 + j) ? S[kt][j] : -3.0e38f;
            }
            f32x4 rm;
            #pragma unroll
            for (int j = 0; j < 4; j++)
                rm[j] = fmaxf(fmaxf(S[0][j], S[1][j]), fmaxf(S[2][j], S[3][j]));
            #pragma unroll
            for (int msk = 1; msk <= 8; msk <<= 1)
                #pragma unroll
                for (int j = 0; j < 4; j++)
                    rm[j] = fmaxf(rm[j], __shfl_xor(rm[j], msk));
            bool grow = false;
            #pragma unroll
            for (int j = 0; j < 4; j++) grow = grow || (rm[j] > mlo[j] + 8.f);
            f32x4 rs = (f32x4){0,0,0,0};
            if (__any(grow)) {
                f32x4 mn, corr;
                #pragma unroll
                for (int j = 0; j < 4; j++) {
                    mn[j] = fmaxf(mlo[j], rm[j]);
                    corr[j] = __expf(mlo[j] - mn[j]);
                }
                #pragma unroll
                for (int kt = 0; kt < 4; kt++)
                    #pragma unroll
                    for (int j = 0; j < 4; j++) {
                        float p = __expf(S[kt][j] - mn[j]);
                        S[kt][j] = p;
                        rs[j] += p;
                    }
                #pragma unroll
                for (int msk = 1; msk <= 8; msk <<= 1)
                    #pragma unroll
                    for (int j = 0; j < 4; j++)
                        rs[j] += __shfl_xor(rs[j], msk);
                #pragma unroll
                for (int j = 0; j < 4; j++) {
                    llo[j] = llo[j] * corr[j] + rs[j];
                    mlo[j] = mn[j];
                }
                #pragma unroll
                for (int dt = 0; dt < 4; dt++)
                    #pragma unroll
                    for (int j = 0; j < 4; j++) Olo[dt][j] *= corr[j];
            } else {
                #pragma unroll
                for (int kt = 0; kt < 4; kt++)
                    #pragma unroll
                    for (int j = 0; j < 4; j++) {
                        float p = __expf(S[kt][j] - mlo[j]);
                        S[kt][j] = p;
                        rs[j] += p;
                    }
                #pragma unroll
                for (int msk = 1; msk <= 8; msk <<= 1)
                    #pragma unroll
                    for (int j = 0; j < 4; j++)
                        rs[j] += __shfl_xor(rs[j], msk);
                #pragma unroll
                for (int j = 0; j < 4; j++) llo[j] += rs[j];
            }
            #pragma unroll
            for (int kt = 0; kt < 4; kt++) {
                int cc = kt * 16 + lr;
                int slot = cc >> 3, off = cc & 7;
                #pragma unroll
                for (int j = 0; j < 4; j++) {
                    int r = hg4 + j;
                    Pw[r * 64 + ((slot ^ (r & 7)) << 3) + off] = f2bf(S[kt][j]);
                }
            }
            asm volatile("s_waitcnt lgkmcnt(0)" ::: "memory");
            bf16x8 pf0 = *(const bf16x8*)&Pw[lr * 64 + ((hg ^ (lr & 7)) << 3)];
            bf16x8 pf1 = *(const bf16x8*)&Pw[lr * 64 + (((4 + hg) ^ (lr & 7)) << 3)];
            __builtin_amdgcn_s_setprio(1);
            #pragma unroll
            for (int dt = 0; dt < 4; dt++) {
                Olo[dt] = __builtin_amdgcn_mfma_f32_16x16x32_bf16(pf0, vfr[2 * dt], Olo[dt], 0, 0, 0);
                Olo[dt] = __builtin_amdgcn_mfma_f32_16x16x32_bf16(pf1, vfr[2 * dt + 1], Olo[dt], 0, 0, 0);
            }
            __builtin_amdgcn_s_setprio(0);
        }
        #pragma unroll
        for (int i = 0; i < 8; i++) kfa[i] = kfb[i];
    }

    // write partials: ti=0 -> lo(pr), ti=1 -> hi(63-pr)
    if (lr == 0) {
        #pragma unroll
        for (int j = 0; j < 4; j++) {
            sm_m[w][0][hg4 + j] = mlo[j];
            sm_l[w][0][hg4 + j] = llo[j];
            sm_m[w][1][hg4 + j] = mhi[j];
            sm_l[w][1][hg4 + j] = lhi[j];
        }
    }
    #pragma unroll
    for (int dt = 0; dt < 4; dt++)
        #pragma unroll
        for (int j = 0; j < 4; j++) {
            sm_o[w][0][hg4 + j][dt * 16 + lr] = Olo[dt][j];
            sm_o[w][1][hg4 + j][dt * 16 + lr] = Ohi[dt][j];
        }
    __syncthreads();
    {
        int ti2 = w >> 1;
        int tile = ti2 ? (63 - pr) : pr;
        int q0 = tile * 16;
        #pragma unroll
        for (int jj = 0; jj < 2; jj++) {
            int j = (w & 1) * 2 + jj;
            int r = hg4 + j;
            float m0 = sm_m[0][ti2][r], m1 = sm_m[1][ti2][r];
            float m2 = sm_m[2][ti2][r], m3 = sm_m[3][ti2][r];
            float M = fmaxf(fmaxf(m0, m1), fmaxf(m2, m3));
            float e0 = __expf(m0 - M), e1 = __expf(m1 - M);
            float e2 = __expf(m2 - M), e3 = __expf(m3 - M);
            float L = sm_l[0][ti2][r] * e0 + sm_l[1][ti2][r] * e1
                    + sm_l[2][ti2][r] * e2 + sm_l[3][ti2][r] * e3;
            float invL = 1.f / L;
            unsigned short* orow = att + ((size_t)(b * SEQ + q0 + r)) * D_MODEL + h * 64;
            #pragma unroll
            for (int dt = 0; dt < 4; dt++) {
                int cidx = dt * 16 + lr;
                float o = sm_o[0][ti2][r][cidx] * e0 + sm_o[1][ti2][r][cidx] * e1
                        + sm_o[2][ti2][r][cidx] * e2 + sm_o[3][ti2][r][cidx] * e3;
                orow[cidx] = f2bf(o * invL);
            }
        }
    }
}

extern "C" void kernel_launch(void* const* d_in, const int* in_sizes, int n_in,
                              void* d_out, int out_size, void* d_ws, size_t ws_size,
                              hipStream_t stream) {
    const int*   input_ids = (const int*)d_in[0];
    const float* token_emb = (const float*)d_in[1];
    const float* pos_emb   = (const float*)d_in[2];
    const float* ln1_g     = (const float*)d_in[3];
    const float* ln1_b     = (const float*)d_in[4];
    const float* qkv_w     = (const float*)d_in[5];
    const float* out_w     = (const float*)d_in[6];
    const float* ln2_g     = (const float*)d_in[7];
    const float* ln2_b     = (const float*)d_in[8];
    const float* ff1_w     = (const float*)d_in[9];
    const float* ff2_w     = (const float*)d_in[10];
    const float* lnf_g     = (const float*)d_in[11];
    const float* lnf_b     = (const float*)d_in[12];
    float* out = (float*)d_out;

    const size_t SZ_QKV_L = (size_t)3 * D_MODEL * D_MODEL;
    const size_t SZ_OUT_L = (size_t)D_MODEL * D_MODEL;
    const size_t SZ_FF1_L = (size_t)FF_DIM * D_MODEL;
    const size_t SZ_FF2_L = (size_t)D_MODEL * FF_DIM;
    const size_t SZ_TOK   = (size_t)VOCAB * D_MODEL;

    char* base = (char*)d_ws;
    size_t off = 0;
    auto alloc = [&](size_t bytes) -> char* {
        char* p = base + off;
        off = (off + bytes + 255) & ~(size_t)255;
        return p;
    };

    float* x              = (float*)alloc((size_t)TOKENS * D_MODEL * 4);
    unsigned short* hb    = (unsigned short*)alloc((size_t)TOKENS * D_MODEL * 2);
    unsigned short* attb  = (unsigned short*)alloc((size_t)TOKENS * D_MODEL * 2);
    unsigned short* ffab  = (unsigned short*)alloc((size_t)TOKENS * FF_DIM * 2);
    unsigned short* Qb    = (unsigned short*)alloc((size_t)TOKENS * D_MODEL * 2);
    unsigned short* Kb    = (unsigned short*)alloc((size_t)TOKENS * D_MODEL * 2);
    unsigned short* Vtb   = (unsigned short*)alloc((size_t)TOKENS * D_MODEL * 2);

    size_t act_end = off;
    size_t full_need = act_end + 2 * (NLAYER * (SZ_QKV_L + SZ_OUT_L + SZ_FF1_L + SZ_FF2_L) + SZ_TOK)
                       + 6 * 256;
    bool full = ws_size >= full_need;

    unsigned short *qkvA, *outA, *ff1A, *ff2A, *tokA;
    if (full) {
        qkvA = (unsigned short*)alloc(2 * NLAYER * SZ_QKV_L);
        outA = (unsigned short*)alloc(2 * NLAYER * SZ_OUT_L);
        ff1A = (unsigned short*)alloc(2 * NLAYER * SZ_FF1_L);
        ff2A = (unsigned short*)alloc(2 * NLAYER * SZ_FF2_L);
        tokA = (unsigned short*)alloc(2 * SZ_TOK);
    } else {
        qkvA = (unsigned short*)alloc(2 * SZ_QKV_L);
        outA = (unsigned short*)alloc(2 * SZ_OUT_L);
        ff1A = (unsigned short*)alloc(2 * SZ_FF1_L);
        ff2A = (unsigned short*)alloc(2 * SZ_FF2_L);
        tokA = (unsigned short*)alloc(2 * SZ_TOK);
    }

    auto cvt = [&](const float* s, unsigned short* d, size_t n) {
        long n4 = (long)(n / 4);
        int g = (int)((n4 + 255) / 256);
        if (g > 2048) g = 2048;
        cvt_kernel<<<g, 256, 0, stream>>>(s, d, n4);
    };

    if (full) {
        cvt(qkv_w, qkvA, NLAYER * SZ_QKV_L);
        cvt(out_w, outA, NLAYER * SZ_OUT_L);
        cvt(ff1_w, ff1A, NLAYER * SZ_FF1_L);
        cvt(ff2_w, ff2A, NLAYER * SZ_FF2_L);
        cvt(token_emb, tokA, SZ_TOK);
    }

    embed_kernel<<<TOKENS * D_MODEL / 256, 256, 0, stream>>>(input_ids, token_emb, pos_emb, x);

    for (int l = 0; l < NLAYER; l++) {
        const unsigned short* qw = full ? qkvA + (size_t)l * SZ_QKV_L : qkvA;
        const unsigned short* ow = full ? outA + (size_t)l * SZ_OUT_L : outA;
        const unsigned short* f1 = full ? ff1A + (size_t)l * SZ_FF1_L : ff1A;
        const unsigned short* f2 = full ? ff2A + (size_t)l * SZ_FF2_L : ff2A;

        ln_kernel<<<TOKENS, 256, 0, stream>>>(x, ln1_g + l * D_MODEL, ln1_b + l * D_MODEL, hb);
        if (!full) cvt(qkv_w + (size_t)l * SZ_QKV_L, qkvA, SZ_QKV_L);
        gemm_bf16<2, 3, GM_QKV, 2><<<dim3(TOKENS / 64, 3 * D_MODEL / 96), 256, 0, stream>>>(
            hb, qw, TOKENS, 3 * D_MODEL, D_MODEL, nullptr, Vtb, nullptr, Qb, Kb);
        attn_mfma<<<dim3(32, NHEAD, 2), 256, 0, stream>>>(Qb, Kb, Vtb, attb);
        if (!full) cvt(out_w + (size_t)l * SZ_OUT_L, outA, SZ_OUT_L);
        gemm_bf16<1, 2, GM_RES, 2><<<dim3(TOKENS / 32, D_MODEL / 64), 256, 0, stream>>>(
            attb, ow, TOKENS, D_MODEL, D_MODEL, x, nullptr, x, nullptr, nullptr);
        ln_kernel<<<TOKENS, 256, 0, stream>>>(x, ln2_g + l * D_MODEL, ln2_b + l * D_MODEL, hb);
        if (!full) cvt(ff1_w + (size_t)l * SZ_FF1_L, ff1A, SZ_FF1_L);
        gemm_bf16<2, 4, GM_GELU, 2><<<dim3(TOKENS / 64, FF_DIM / 128), 256, 0, stream>>>(
            hb, f1, TOKENS, FF_DIM, D_MODEL, nullptr, ffab, nullptr, nullptr, nullptr);
        if (!full) cvt(ff2_w + (size_t)l * SZ_FF2_L, ff2A, SZ_FF2_L);
        gemm_bf16<1, 2, GM_RES, 2><<<dim3(TOKENS / 32, D_MODEL / 64), 256, 0, stream>>>(
            ffab, f2, TOKENS, D_MODEL, FF_DIM, x, nullptr, x, nullptr, nullptr);
    }

    ln_kernel<<<TOKENS, 256, 0, stream>>>(x, lnf_g, lnf_b, hb);
    if (!full) cvt(token_emb, tokA, SZ_TOK);
    // 256^2 / BK=64 / 8-wave (r15 proven: 296 us)
    gemm256_bf16<<<dim3(TOKENS / 256, (VOCAB + 255) / 256), 512, 0, stream>>>(
        hb, tokA, TOKENS, VOCAB, D_MODEL, out);
}

// Round 20
// 1986.780 us; speedup vs baseline: 1.0088x; 1.0088x over previous
//
#include <hip/hip_runtime.h>
#include <hip/hip_bf16.h>
#include <math.h>

#define D_MODEL 768
#define NHEAD 12
#define DHEAD 64
#define NLAYER 12
#define FF_DIM 3072
#define SEQ 1024
#define TOKENS 2048   /* B*T */
#define VOCAB 50257

typedef short bf16x8 __attribute__((ext_vector_type(8)));
typedef float f32x4 __attribute__((ext_vector_type(4)));
typedef unsigned short u16x4 __attribute__((ext_vector_type(4)));
typedef unsigned short u16x8 __attribute__((ext_vector_type(8)));

__device__ inline unsigned short f2bf(float f) {
    union { float f; unsigned u; } un;
    un.f = f;
    unsigned u = un.u;
    u += 0x7fffu + ((u >> 16) & 1u);   // RTNE
    return (unsigned short)(u >> 16);
}

// async 16B global->LDS (dest must be wave-uniform base; HW adds lane*16)
__device__ inline void gl_lds16(const void* g, void* l) {
    __builtin_amdgcn_global_load_lds(
        (const __attribute__((address_space(1))) unsigned int*)g,
        (__attribute__((address_space(3))) unsigned int*)l, 16, 0, 0);
}

// counted vmcnt wait (T4): immediate must be a literal
template<int N> __device__ __forceinline__ void waitcnt_vm() {
    static_assert(N == 0 || N == 3 || N == 4 || N == 5 || N == 6 || N == 8, "add case");
    if constexpr (N == 0) asm volatile("s_waitcnt vmcnt(0)" ::: "memory");
    else if constexpr (N == 3) asm volatile("s_waitcnt vmcnt(3)" ::: "memory");
    else if constexpr (N == 4) asm volatile("s_waitcnt vmcnt(4)" ::: "memory");
    else if constexpr (N == 5) asm volatile("s_waitcnt vmcnt(5)" ::: "memory");
    else if constexpr (N == 6) asm volatile("s_waitcnt vmcnt(6)" ::: "memory");
    else if constexpr (N == 8) asm volatile("s_waitcnt vmcnt(8)" ::: "memory");
}

// ---------------- fp32 -> bf16 bulk convert ----------------
__global__ __launch_bounds__(256) void cvt_kernel(const float* __restrict__ s,
                                                  unsigned short* __restrict__ d,
                                                  long n4) {
    long i = (long)blockIdx.x * 256 + threadIdx.x;
    long stride = (long)gridDim.x * 256;
    for (; i < n4; i += stride) {
        f32x4 v = ((const f32x4*)s)[i];
        u16x4 r;
        r[0] = f2bf(v[0]); r[1] = f2bf(v[1]); r[2] = f2bf(v[2]); r[3] = f2bf(v[3]);
        ((u16x4*)d)[i] = r;
    }
}

// ---------------- embedding ----------------
__global__ __launch_bounds__(256) void embed_kernel(const int* __restrict__ ids,
                                                    const float* __restrict__ tok,
                                                    const float* __restrict__ pos,
                                                    float* __restrict__ x) {
    int i = blockIdx.x * 256 + threadIdx.x;          // over TOKENS*D_MODEL
    int row = i / D_MODEL;
    int d = i - row * D_MODEL;
    int t = row & (SEQ - 1);
    x[i] = tok[(long)ids[row] * D_MODEL + d] + pos[(long)t * D_MODEL + d];
}

// ---------------- layernorm (fp32 in, bf16 out) ----------------
__global__ __launch_bounds__(256) void ln_kernel(const float* __restrict__ x,
                                                 const float* __restrict__ g,
                                                 const float* __restrict__ b,
                                                 unsigned short* __restrict__ out) {
    int row = blockIdx.x;
    int tid = threadIdx.x;
    const float* xr = x + (long)row * D_MODEL;
    float v0 = xr[tid], v1 = xr[tid + 256], v2 = xr[tid + 512];
    __shared__ float sm[4];
    float s = v0 + v1 + v2;
    #pragma unroll
    for (int off = 32; off; off >>= 1) s += __shfl_xor(s, off);
    if ((tid & 63) == 0) sm[tid >> 6] = s;
    __syncthreads();
    float mean = (sm[0] + sm[1] + sm[2] + sm[3]) * (1.f / D_MODEL);
    __syncthreads();
    float d0 = v0 - mean, d1 = v1 - mean, d2 = v2 - mean;
    s = d0 * d0 + d1 * d1 + d2 * d2;
    #pragma unroll
    for (int off = 32; off; off >>= 1) s += __shfl_xor(s, off);
    if ((tid & 63) == 0) sm[tid >> 6] = s;
    __syncthreads();
    float var = (sm[0] + sm[1] + sm[2] + sm[3]) * (1.f / D_MODEL);
    float rs = rsqrtf(var + 1e-5f);
    unsigned short* orow = out + (long)row * D_MODEL;
    orow[tid]       = f2bf(d0 * rs * g[tid]       + b[tid]);
    orow[tid + 256] = f2bf(d1 * rs * g[tid + 256] + b[tid + 256]);
    orow[tid + 512] = f2bf(d2 * rs * g[tid + 512] + b[tid + 512]);
}

// ---------------- GEMM: C[M][N] = A_bf16[M][K] @ W_bf16[N][K]^T ----------------
// DB=2 + counted vmcnt (T4). Slot-XOR swizzle both sides (rule #21) -> 0 bank
// conflicts. Tile law (r13/r14): chip-filling grids -> maximize frag-reuse;
// small grids (N=768) -> maximize block count (<1,2>, 768 blk = 3/CU).
#define GM_NONE 0
#define GM_RES  1
#define GM_GELU 2
#define GM_QKV  3

template<int WM, int WN, int MODE, int DB>
__global__ __launch_bounds__(256) void gemm_bf16(
        const unsigned short* __restrict__ A, const unsigned short* __restrict__ W,
        int M, int N, int K,
        float* __restrict__ Cf, unsigned short* __restrict__ Cb,
        const float* __restrict__ RES,
        unsigned short* __restrict__ P1, unsigned short* __restrict__ P2) {
    constexpr int BM = WM * 32, BN = WN * 32;
    constexpr int NLD = BM / 32 + BN / 32;   // gl_lds issues per stage()
    __shared__ unsigned short lA[DB][BM * 64];
    __shared__ unsigned short lB[DB][BN * 64];

    int tid = threadIdx.x;
    int lane = tid & 63, wv = tid >> 6;
    int wr = wv >> 1, wc = wv & 1;
    int lr = lane & 15, kq = lane >> 4;
    int row0 = blockIdx.x * BM;
    int col0 = blockIdx.y * BN;

    int srow_in = tid >> 3;
    int ssp = tid & 7;
    int skg = ssp ^ (srow_in & 7);
    int lbase = ((tid & ~63)) << 3;

    f32x4 acc[WM][WN];
    #pragma unroll
    for (int m = 0; m < WM; m++)
        #pragma unroll
        for (int n = 0; n < WN; n++) acc[m][n] = (f32x4){0.f, 0.f, 0.f, 0.f};

    auto stage = [&](int buf, int kt) {
        #pragma unroll
        for (int i = 0; i < BM / 32; i++) {
            int row = i * 32 + srow_in;
            gl_lds16(A + (size_t)(row0 + row) * K + kt + skg * 8,
                     &lA[buf][i * 2048 + lbase]);
        }
        #pragma unroll
        for (int i = 0; i < BN / 32; i++) {
            int row = i * 32 + srow_in;
            int srow = col0 + row;
            if (srow >= N) srow = N - 1;
            gl_lds16(W + (size_t)srow * K + kt + skg * 8,
                     &lB[buf][i * 2048 + lbase]);
        }
    };
    auto compute = [&](int buf) {
        #pragma unroll
        for (int kk = 0; kk < 2; kk++) {
            int kg = kk * 4 + kq;
            bf16x8 af[WM], bfr[WN];
            #pragma unroll
            for (int m = 0; m < WM; m++) {
                int row = wr * (WM * 16) + m * 16 + lr;
                af[m] = *(const bf16x8*)&lA[buf][row * 64 + ((kg ^ (row & 7)) << 3)];
            }
            #pragma unroll
            for (int n = 0; n < WN; n++) {
                int row = wc * (WN * 16) + n * 16 + lr;
                bfr[n] = *(const bf16x8*)&lB[buf][row * 64 + ((kg ^ (row & 7)) << 3)];
            }
            #pragma unroll
            for (int m = 0; m < WM; m++)
                #pragma unroll
                for (int n = 0; n < WN; n++)
                    acc[m][n] = __builtin_amdgcn_mfma_f32_16x16x32_bf16(af[m], bfr[n], acc[m][n], 0, 0, 0);
        }
    };

    if (DB == 2) {
        stage(0, 0);
        __builtin_amdgcn_sched_barrier(0);
        int nt = K >> 6;
        int cur = 0;
        for (int t = 0; t < nt; t++) {
            if (t + 1 < nt) {
                stage(cur ^ 1, (t + 1) << 6);
                __builtin_amdgcn_sched_barrier(0);
                waitcnt_vm<NLD>();      // tile t's loads done; t+1's stay in flight
            } else {
                waitcnt_vm<0>();
            }
            __builtin_amdgcn_s_barrier();
            __builtin_amdgcn_sched_barrier(0);
            compute(cur);
            __builtin_amdgcn_sched_barrier(0);
            __builtin_amdgcn_s_barrier();   // WAR: all reads of cur done before re-stage
            cur ^= 1;
        }
    } else {
        for (int kt = 0; kt < K; kt += 64) {
            stage(0, kt);
            __syncthreads();
            compute(0);
            __syncthreads();
        }
    }

    // ---- epilogue ----
    #pragma unroll
    for (int m = 0; m < WM; m++) {
        int r0 = row0 + wr * (WM * 16) + m * 16 + (kq << 2);
        #pragma unroll
        for (int n = 0; n < WN; n++) {
            int c = col0 + wc * (WN * 16) + n * 16 + lr;
            if (c < N) {
                if (MODE == GM_QKV) {
                    int bb = r0 >> 10, t0q = r0 & 1023;   // 4 consecutive tokens, same b
                    if (c < D_MODEL) {
                        int h = c >> 6, dh = c & 63;
                        size_t base = (((size_t)(bb * NHEAD + h) * SEQ) + t0q) * 64 + dh;
                        #pragma unroll
                        for (int j = 0; j < 4; j++)
                            P1[base + (size_t)j * 64] = f2bf(acc[m][n][j] * 0.125f);
                    } else if (c < 2 * D_MODEL) {
                        int cc = c - D_MODEL;
                        int h = cc >> 6, dh = cc & 63;
                        size_t base = (((size_t)(bb * NHEAD + h) * SEQ) + t0q) * 64 + dh;
                        #pragma unroll
                        for (int j = 0; j < 4; j++)
                            P2[base + (size_t)j * 64] = f2bf(acc[m][n][j]);
                    } else {
                        int cc = c - 2 * D_MODEL;
                        int h = cc >> 6, dh = cc & 63;
                        u16x4 vv;
                        #pragma unroll
                        for (int j = 0; j < 4; j++) vv[j] = f2bf(acc[m][n][j]);
                        *(u16x4*)(Cb + ((size_t)(bb * NHEAD + h) * 64 + dh) * SEQ + t0q) = vv;
                    }
                } else {
                    #pragma unroll
                    for (int j = 0; j < 4; j++) {
                        int r = r0 + j;
                        size_t idx = (size_t)r * N + c;
                        float v = acc[m][n][j];
                        if (MODE == GM_RES) {
                            Cf[idx] = v + RES[idx];
                        } else if (MODE == GM_GELU) {
                            Cb[idx] = f2bf(0.5f * v * (1.f + erff(v * 0.70710678118f)));
                        } else {
                            Cf[idx] = v;
                        }
                    }
                }
            }
        }
    }
}

// ---------------- 256x256 GEMM for the logits shape (r15 proven: 296us) ----------------
// 8 waves (2Mx4N), wave-tile 128x64: -25% LDS bytes/FLOP vs 128^2/<4,4>.
__global__ __launch_bounds__(512, 2) void gemm256_bf16(
        const unsigned short* __restrict__ A, const unsigned short* __restrict__ W,
        int M, int N, int K, float* __restrict__ Cf) {
    __shared__ unsigned short lA[2][256 * 64];   // 64 KB
    __shared__ unsigned short lB[2][256 * 64];   // 64 KB

    int tid = threadIdx.x;
    int lane = tid & 63, wv = tid >> 6;
    int wr = wv >> 2, wc = wv & 3;               // 2 x 4 waves
    int lr = lane & 15, kq = lane >> 4;
    int row0 = blockIdx.x * 256;
    int col0 = blockIdx.y * 256;

    int srow_in = tid >> 3;                      // 0..63 per issue
    int skg = (tid & 7) ^ (srow_in & 7);
    int lbase = (tid & ~63) << 3;                // wv*512 ushorts

    f32x4 acc[8][4];
    #pragma unroll
    for (int m = 0; m < 8; m++)
        #pragma unroll
        for (int n = 0; n < 4; n++) acc[m][n] = (f32x4){0.f, 0.f, 0.f, 0.f};

    auto stage = [&](int buf, int kt) {
        #pragma unroll
        for (int i = 0; i < 4; i++) {
            int row = i * 64 + srow_in;
            gl_lds16(A + (size_t)(row0 + row) * K + kt + skg * 8,
                     &lA[buf][i * 4096 + lbase]);
        }
        #pragma unroll
        for (int i = 0; i < 4; i++) {
            int row = i * 64 + srow_in;
            int srow = col0 + row;
            if (srow >= N) srow = N - 1;
            gl_lds16(W + (size_t)srow * K + kt + skg * 8,
                     &lB[buf][i * 4096 + lbase]);
        }
    };
    auto compute = [&](int buf) {
        #pragma unroll
        for (int kk = 0; kk < 2; kk++) {
            int kg = kk * 4 + kq;
            bf16x8 af[8], bfr[4];
            #pragma unroll
            for (int m = 0; m < 8; m++) {
                int row = wr * 128 + m * 16 + lr;
                af[m] = *(const bf16x8*)&lA[buf][row * 64 + ((kg ^ (row & 7)) << 3)];
            }
            #pragma unroll
            for (int n = 0; n < 4; n++) {
                int row = wc * 64 + n * 16 + lr;
                bfr[n] = *(const bf16x8*)&lB[buf][row * 64 + ((kg ^ (row & 7)) << 3)];
            }
            #pragma unroll
            for (int m = 0; m < 8; m++)
                #pragma unroll
                for (int n = 0; n < 4; n++)
                    acc[m][n] = __builtin_amdgcn_mfma_f32_16x16x32_bf16(af[m], bfr[n], acc[m][n], 0, 0, 0);
        }
    };

    stage(0, 0);
    __builtin_amdgcn_sched_barrier(0);
    int nt = K >> 6;
    int cur = 0;
    for (int t = 0; t < nt; t++) {
        if (t + 1 < nt) {
            stage(cur ^ 1, (t + 1) << 6);
            __builtin_amdgcn_sched_barrier(0);
            waitcnt_vm<8>();             // tile t's 8 loads done; t+1's in flight
        } else {
            waitcnt_vm<0>();
        }
        __builtin_amdgcn_s_barrier();
        __builtin_amdgcn_sched_barrier(0);
        compute(cur);
        __builtin_amdgcn_sched_barrier(0);
        __builtin_amdgcn_s_barrier();
        cur ^= 1;
    }

    #pragma unroll
    for (int m = 0; m < 8; m++) {
        int r0 = row0 + wr * 128 + m * 16 + (kq << 2);
        #pragma unroll
        for (int n = 0; n < 4; n++) {
            int c = col0 + wc * 64 + n * 16 + lr;
            if (c < N) {
                #pragma unroll
                for (int j = 0; j < 4; j++)
                    Cf[(size_t)(r0 + j) * N + c] = acc[m][n][j];
            }
        }
    }
}

// ---------------- MFMA flash attention (r16 best: two-pass + K-prefetch + V-hoist) ----------------
#define ANW 4
__global__ __launch_bounds__(256) void attn_mfma(const unsigned short* __restrict__ Qb,
                                                 const unsigned short* __restrict__ Kb,
                                                 const unsigned short* __restrict__ Vt,
                                                 unsigned short* __restrict__ att) {
    int b = blockIdx.z, h = blockIdx.y, pr = blockIdx.x;
    int tid = threadIdx.x, l = tid & 63, w = tid >> 6;
    int lr = l & 15, hg = l >> 4;
    int hk8 = hg * 8, hg4 = hg * 4;
    size_t bh = (size_t)b * NHEAD + h;
    const unsigned short* Qp = Qb + bh * SEQ * 64;
    const unsigned short* Kp = Kb + bh * SEQ * 64;
    const unsigned short* Vp = Vt + bh * 64 * SEQ;

    __shared__ float sm_m[ANW][2][16], sm_l[ANW][2][16];
    __shared__ float sm_o[ANW][2][16][65];
    __shared__ unsigned short pl[ANW][1024];
    unsigned short* Pw = &pl[w][0];

    #pragma unroll
    for (int ti = 0; ti < 2; ti++) {
        int tile = ti ? (63 - pr) : pr;
        int q0 = tile * 16;
        bf16x8 qf0 = *(const bf16x8*)(Qp + (size_t)(q0 + lr) * 64 + hk8);
        bf16x8 qf1 = *(const bf16x8*)(Qp + (size_t)(q0 + lr) * 64 + 32 + hk8);
        f32x4 O[4];
        #pragma unroll
        for (int dt = 0; dt < 4; dt++) O[dt] = (f32x4){0.f, 0.f, 0.f, 0.f};
        f32x4 mrun = (f32x4){-1e30f, -1e30f, -1e30f, -1e30f};
        f32x4 lrun = (f32x4){0.f, 0.f, 0.f, 0.f};
        int nch = (tile >> 2) + 1;

        bf16x8 kfa[8];
        if (w < nch) {
            int k0p = w * 64;
            #pragma unroll
            for (int kt = 0; kt < 4; kt++) {
                kfa[2 * kt]     = *(const bf16x8*)(Kp + (size_t)(k0p + kt * 16 + lr) * 64 + hk8);
                kfa[2 * kt + 1] = *(const bf16x8*)(Kp + (size_t)(k0p + kt * 16 + lr) * 64 + 32 + hk8);
            }
        }

        for (int c = w; c < nch; c += ANW) {
            int k0 = c * 64;
            f32x4 S[4];
            #pragma unroll
            for (int kt = 0; kt < 4; kt++) {
                S[kt] = (f32x4){0.f, 0.f, 0.f, 0.f};
                S[kt] = __builtin_amdgcn_mfma_f32_16x16x32_bf16(qf0, kfa[2 * kt], S[kt], 0, 0, 0);
                S[kt] = __builtin_amdgcn_mfma_f32_16x16x32_bf16(qf1, kfa[2 * kt + 1], S[kt], 0, 0, 0);
            }
            bf16x8 kfb[8];
            int cn = c + ANW;
            if (cn < nch) {
                int k0n = cn * 64;
                #pragma unroll
                for (int kt = 0; kt < 4; kt++) {
                    kfb[2 * kt]     = *(const bf16x8*)(Kp + (size_t)(k0n + kt * 16 + lr) * 64 + hk8);
                    kfb[2 * kt + 1] = *(const bf16x8*)(Kp + (size_t)(k0n + kt * 16 + lr) * 64 + 32 + hk8);
                }
            }
            if (c == nch - 1) {
                #pragma unroll
                for (int kt = 0; kt < 4; kt++)
                    #pragma unroll
                    for (int j = 0; j < 4; j++)
                        S[kt][j] = (k0 + kt * 16 + lr <= q0 + hg4 + j) ? S[kt][j] : -3.0e38f;
            }
            f32x4 rm;
            #pragma unroll
            for (int j = 0; j < 4; j++)
                rm[j] = fmaxf(fmaxf(S[0][j], S[1][j]), fmaxf(S[2][j], S[3][j]));
            #pragma unroll
            for (int msk = 1; msk <= 8; msk <<= 1)
                #pragma unroll
                for (int j = 0; j < 4; j++)
                    rm[j] = fmaxf(rm[j], __shfl_xor(rm[j], msk));
            f32x4 mn, corr, rs;
            #pragma unroll
            for (int j = 0; j < 4; j++) {
                mn[j] = fmaxf(mrun[j], rm[j]);
                corr[j] = __expf(mrun[j] - mn[j]);
                rs[j] = 0.f;
            }
            #pragma unroll
            for (int kt = 0; kt < 4; kt++)
                #pragma unroll
                for (int j = 0; j < 4; j++) {
                    float p = __expf(S[kt][j] - mn[j]);
                    S[kt][j] = p;
                    rs[j] += p;
                }
            #pragma unroll
            for (int msk = 1; msk <= 8; msk <<= 1)
                #pragma unroll
                for (int j = 0; j < 4; j++)
                    rs[j] += __shfl_xor(rs[j], msk);
            #pragma unroll
            for (int j = 0; j < 4; j++) {
                lrun[j] = lrun[j] * corr[j] + rs[j];
                mrun[j] = mn[j];
            }
            #pragma unroll
            for (int dt = 0; dt < 4; dt++)
                #pragma unroll
                for (int j = 0; j < 4; j++) O[dt][j] *= corr[j];
            bf16x8 vfr[8];
            #pragma unroll
            for (int dt = 0; dt < 4; dt++) {
                vfr[2 * dt]     = *(const bf16x8*)(Vp + (size_t)(dt * 16 + lr) * SEQ + k0 + hk8);
                vfr[2 * dt + 1] = *(const bf16x8*)(Vp + (size_t)(dt * 16 + lr) * SEQ + k0 + 32 + hk8);
            }
            #pragma unroll
            for (int kt = 0; kt < 4; kt++) {
                int cc = kt * 16 + lr;
                int slot = cc >> 3, off = cc & 7;
                #pragma unroll
                for (int j = 0; j < 4; j++) {
                    int r = hg4 + j;
                    Pw[r * 64 + ((slot ^ (r & 7)) << 3) + off] = f2bf(S[kt][j]);
                }
            }
            asm volatile("s_waitcnt lgkmcnt(0)" ::: "memory");
            bf16x8 pf0 = *(const bf16x8*)&Pw[lr * 64 + ((hg ^ (lr & 7)) << 3)];
            bf16x8 pf1 = *(const bf16x8*)&Pw[lr * 64 + (((4 + hg) ^ (lr & 7)) << 3)];
            #pragma unroll
            for (int dt = 0; dt < 4; dt++) {
                O[dt] = __builtin_amdgcn_mfma_f32_16x16x32_bf16(pf0, vfr[2 * dt], O[dt], 0, 0, 0);
                O[dt] = __builtin_amdgcn_mfma_f32_16x16x32_bf16(pf1, vfr[2 * dt + 1], O[dt], 0, 0, 0);
            }
            #pragma unroll
            for (int i = 0; i < 8; i++) kfa[i] = kfb[i];
        }
        if (lr == 0) {
            #pragma unroll
            for (int j = 0; j < 4; j++) {
                sm_m[w][ti][hg4 + j] = mrun[j];
                sm_l[w][ti][hg4 + j] = lrun[j];
            }
        }
        #pragma unroll
        for (int dt = 0; dt < 4; dt++)
            #pragma unroll
            for (int j = 0; j < 4; j++)
                sm_o[w][ti][hg4 + j][dt * 16 + lr] = O[dt][j];
    }
    __syncthreads();
    {
        int ti2 = w >> 1;
        int tile = ti2 ? (63 - pr) : pr;
        int q0 = tile * 16;
        #pragma unroll
        for (int jj = 0; jj < 2; jj++) {
            int j = (w & 1) * 2 + jj;
            int r = hg4 + j;
            float m0 = sm_m[0][ti2][r], m1 = sm_m[1][ti2][r];
            float m2 = sm_m[2][ti2][r], m3 = sm_m[3][ti2][r];
            float M = fmaxf(fmaxf(m0, m1), fmaxf(m2, m3));
            float e0 = __expf(m0 - M), e1 = __expf(m1 - M);
            float e2 = __expf(m2 - M), e3 = __expf(m3 - M);
            float L = sm_l[0][ti2][r] * e0 + sm_l[1][ti2][r] * e1
                    + sm_l[2][ti2][r] * e2 + sm_l[3][ti2][r] * e3;
            float invL = 1.f / L;
            unsigned short* orow = att + ((size_t)(b * SEQ + q0 + r)) * D_MODEL + h * 64;
            #pragma unroll
            for (int dt = 0; dt < 4; dt++) {
                int cidx = dt * 16 + lr;
                float o = sm_o[0][ti2][r][cidx] * e0 + sm_o[1][ti2][r][cidx] * e1
                        + sm_o[2][ti2][r][cidx] * e2 + sm_o[3][ti2][r][cidx] * e3;
                orow[cidx] = f2bf(o * invL);
            }
        }
    }
}

extern "C" void kernel_launch(void* const* d_in, const int* in_sizes, int n_in,
                              void* d_out, int out_size, void* d_ws, size_t ws_size,
                              hipStream_t stream) {
    const int*   input_ids = (const int*)d_in[0];
    const float* token_emb = (const float*)d_in[1];
    const float* pos_emb   = (const float*)d_in[2];
    const float* ln1_g     = (const float*)d_in[3];
    const float* ln1_b     = (const float*)d_in[4];
    const float* qkv_w     = (const float*)d_in[5];
    const float* out_w     = (const float*)d_in[6];
    const float* ln2_g     = (const float*)d_in[7];
    const float* ln2_b     = (const float*)d_in[8];
    const float* ff1_w     = (const float*)d_in[9];
    const float* ff2_w     = (const float*)d_in[10];
    const float* lnf_g     = (const float*)d_in[11];
    const float* lnf_b     = (const float*)d_in[12];
    float* out = (float*)d_out;

    const size_t SZ_QKV_L = (size_t)3 * D_MODEL * D_MODEL;
    const size_t SZ_OUT_L = (size_t)D_MODEL * D_MODEL;
    const size_t SZ_FF1_L = (size_t)FF_DIM * D_MODEL;
    const size_t SZ_FF2_L = (size_t)D_MODEL * FF_DIM;
    const size_t SZ_TOK   = (size_t)VOCAB * D_MODEL;

    char* base = (char*)d_ws;
    size_t off = 0;
    auto alloc = [&](size_t bytes) -> char* {
        char* p = base + off;
        off = (off + bytes + 255) & ~(size_t)255;
        return p;
    };

    float* x              = (float*)alloc((size_t)TOKENS * D_MODEL * 4);
    unsigned short* hb    = (unsigned short*)alloc((size_t)TOKENS * D_MODEL * 2);
    unsigned short* attb  = (unsigned short*)alloc((size_t)TOKENS * D_MODEL * 2);
    unsigned short* ffab  = (unsigned short*)alloc((size_t)TOKENS * FF_DIM * 2);
    unsigned short* Qb    = (unsigned short*)alloc((size_t)TOKENS * D_MODEL * 2);
    unsigned short* Kb    = (unsigned short*)alloc((size_t)TOKENS * D_MODEL * 2);
    unsigned short* Vtb   = (unsigned short*)alloc((size_t)TOKENS * D_MODEL * 2);

    size_t act_end = off;
    size_t full_need = act_end + 2 * (NLAYER * (SZ_QKV_L + SZ_OUT_L + SZ_FF1_L + SZ_FF2_L) + SZ_TOK)
                       + 6 * 256;
    bool full = ws_size >= full_need;

    unsigned short *qkvA, *outA, *ff1A, *ff2A, *tokA;
    if (full) {
        qkvA = (unsigned short*)alloc(2 * NLAYER * SZ_QKV_L);
        outA = (unsigned short*)alloc(2 * NLAYER * SZ_OUT_L);
        ff1A = (unsigned short*)alloc(2 * NLAYER * SZ_FF1_L);
        ff2A = (unsigned short*)alloc(2 * NLAYER * SZ_FF2_L);
        tokA = (unsigned short*)alloc(2 * SZ_TOK);
    } else {
        qkvA = (unsigned short*)alloc(2 * SZ_QKV_L);
        outA = (unsigned short*)alloc(2 * SZ_OUT_L);
        ff1A = (unsigned short*)alloc(2 * SZ_FF1_L);
        ff2A = (unsigned short*)alloc(2 * SZ_FF2_L);
        tokA = (unsigned short*)alloc(2 * SZ_TOK);
    }

    auto cvt = [&](const float* s, unsigned short* d, size_t n) {
        long n4 = (long)(n / 4);
        int g = (int)((n4 + 255) / 256);
        if (g > 2048) g = 2048;
        cvt_kernel<<<g, 256, 0, stream>>>(s, d, n4);
    };

    if (full) {
        cvt(qkv_w, qkvA, NLAYER * SZ_QKV_L);
        cvt(out_w, outA, NLAYER * SZ_OUT_L);
        cvt(ff1_w, ff1A, NLAYER * SZ_FF1_L);
        cvt(ff2_w, ff2A, NLAYER * SZ_FF2_L);
        cvt(token_emb, tokA, SZ_TOK);
    }

    embed_kernel<<<TOKENS * D_MODEL / 256, 256, 0, stream>>>(input_ids, token_emb, pos_emb, x);

    for (int l = 0; l < NLAYER; l++) {
        const unsigned short* qw = full ? qkvA + (size_t)l * SZ_QKV_L : qkvA;
        const unsigned short* ow = full ? outA + (size_t)l * SZ_OUT_L : outA;
        const unsigned short* f1 = full ? ff1A + (size_t)l * SZ_FF1_L : ff1A;
        const unsigned short* f2 = full ? ff2A + (size_t)l * SZ_FF2_L : ff2A;

        ln_kernel<<<TOKENS, 256, 0, stream>>>(x, ln1_g + l * D_MODEL, ln1_b + l * D_MODEL, hb);
        if (!full) cvt(qkv_w + (size_t)l * SZ_QKV_L, qkvA, SZ_QKV_L);
        gemm_bf16<2, 3, GM_QKV, 2><<<dim3(TOKENS / 64, 3 * D_MODEL / 96), 256, 0, stream>>>(
            hb, qw, TOKENS, 3 * D_MODEL, D_MODEL, nullptr, Vtb, nullptr, Qb, Kb);
        attn_mfma<<<dim3(32, NHEAD, 2), 256, 0, stream>>>(Qb, Kb, Vtb, attb);
        if (!full) cvt(out_w + (size_t)l * SZ_OUT_L, outA, SZ_OUT_L);
        gemm_bf16<1, 2, GM_RES, 2><<<dim3(TOKENS / 32, D_MODEL / 64), 256, 0, stream>>>(
            attb, ow, TOKENS, D_MODEL, D_MODEL, x, nullptr, x, nullptr, nullptr);
        ln_kernel<<<TOKENS, 256, 0, stream>>>(x, ln2_g + l * D_MODEL, ln2_b + l * D_MODEL, hb);
        if (!full) cvt(ff1_w + (size_t)l * SZ_FF1_L, ff1A, SZ_FF1_L);
        gemm_bf16<2, 4, GM_GELU, 2><<<dim3(TOKENS / 64, FF_DIM / 128), 256, 0, stream>>>(
            hb, f1, TOKENS, FF_DIM, D_MODEL, nullptr, ffab, nullptr, nullptr, nullptr);
        if (!full) cvt(ff2_w + (size_t)l * SZ_FF2_L, ff2A, SZ_FF2_L);
        gemm_bf16<1, 2, GM_RES, 2><<<dim3(TOKENS / 32, D_MODEL / 64), 256, 0, stream>>>(
            ffab, f2, TOKENS, D_MODEL, FF_DIM, x, nullptr, x, nullptr, nullptr);
    }

    ln_kernel<<<TOKENS, 256, 0, stream>>>(x, lnf_g, lnf_b, hb);
    if (!full) cvt(token_emb, tokA, SZ_TOK);
    // 256^2 / BK=64 / 8-wave (r15/r16 proven: ~296 us)
    gemm256_bf16<<<dim3(TOKENS / 256, (VOCAB + 255) / 256), 512, 0, stream>>>(
        hb, tokA, TOKENS, VOCAB, D_MODEL, out);
}